// Round 11
// baseline (922.183 us; speedup 1.0000x reference)
//
#include <hip/hip_runtime.h>
#include <hip/hip_fp16.h>

#define NLV 16
#define TBL (1u << 19)
#define TMASK (TBL - 1u)
#define P1 2654435761u
#define P2 805459861u
#define NBIN (1 << 15)   // 32^3 Morton bins

typedef float vf2 __attribute__((ext_vector_type(2)));
typedef float vf4 __attribute__((ext_vector_type(4)));
typedef unsigned vu2 __attribute__((ext_vector_type(2)));

__device__ __forceinline__ vf2 h2_to_f2(unsigned bits) {
    union { unsigned u; __half2 h; } c; c.u = bits;
    float2 f = __half22float2(c.h);
    vf2 r; r.x = f.x; r.y = f.y; return r;
}
__device__ __forceinline__ unsigned f2_to_h2(float a, float b) {
    union { __half2 h; unsigned u; } c; c.h = __floats2half2_rn(a, b);
    return c.u;
}

__device__ __forceinline__ unsigned mort5(unsigned v) {
    v &= 31u;
    v = (v | (v << 16)) & 0x030000FFu;
    v = (v | (v << 8))  & 0x0300F00Fu;
    v = (v | (v << 4))  & 0x030C30C3u;
    v = (v | (v << 2))  & 0x09249249u;
    return v;
}

__device__ __forceinline__ unsigned bin_of(float ux, float uy, float uz) {
    unsigned bx = min(31u, (unsigned)(ux * 32.0f));
    unsigned by = min(31u, (unsigned)(uy * 32.0f));
    unsigned bz = min(31u, (unsigned)(uz * 32.0f));
    return mort5(bx) | (mort5(by) << 1) | (mort5(bz) << 2);
}

// ---------------------------------------------------------------------------
// Pre-pass A: f32 tables -> packed fp16 (u32/entry).
// ---------------------------------------------------------------------------
__global__ __launch_bounds__(256) void convert_tables(
    const float* __restrict__ tables, unsigned* __restrict__ htab, int total)
{
    int i = blockIdx.x * 256 + threadIdx.x;
    int e0 = i * 2;
    if (e0 >= total) return;
    vf4 v = *(const vf4*)(tables + (size_t)e0 * 2);
    vu2 o; o.x = f2_to_h2(v.x, v.y); o.y = f2_to_h2(v.z, v.w);
    *(vu2*)(htab + e0) = o;
}

// ---------------------------------------------------------------------------
// Sort step 1: histogram (4 pts/thread, 3 x vf4 xyz reads).
// ---------------------------------------------------------------------------
__global__ __launch_bounds__(256) void hist_kernel(
    const float* __restrict__ xyz, unsigned* __restrict__ hist, int n)
{
    int t = blockIdx.x * 256 + threadIdx.x;
    int p = t * 4;
    if (p >= n) return;
    if (p + 3 < n) {
        vf4 a = *(const vf4*)(xyz + (size_t)p * 3);
        vf4 b = *(const vf4*)(xyz + (size_t)p * 3 + 4);
        vf4 c = *(const vf4*)(xyz + (size_t)p * 3 + 8);
        atomicAdd(&hist[bin_of(a.x*0.5f+0.5f, a.y*0.5f+0.5f, a.z*0.5f+0.5f)], 1u);
        atomicAdd(&hist[bin_of(a.w*0.5f+0.5f, b.x*0.5f+0.5f, b.y*0.5f+0.5f)], 1u);
        atomicAdd(&hist[bin_of(b.z*0.5f+0.5f, b.w*0.5f+0.5f, c.x*0.5f+0.5f)], 1u);
        atomicAdd(&hist[bin_of(c.y*0.5f+0.5f, c.z*0.5f+0.5f, c.w*0.5f+0.5f)], 1u);
    } else {
        for (int q = 0; q < 4 && p + q < n; ++q) {
            float ux = xyz[(size_t)(p+q)*3+0]*0.5f+0.5f;
            float uy = xyz[(size_t)(p+q)*3+1]*0.5f+0.5f;
            float uz = xyz[(size_t)(p+q)*3+2]*0.5f+0.5f;
            atomicAdd(&hist[bin_of(ux,uy,uz)], 1u);
        }
    }
}

// ---------------------------------------------------------------------------
// Sort step 2: exclusive scan of NBIN counters (single block).
// ---------------------------------------------------------------------------
__global__ __launch_bounds__(1024) void scan_bins(unsigned* __restrict__ hist)
{
    __shared__ unsigned part[1024];
    int t = threadIdx.x;
    int base = t * (NBIN / 1024);
    unsigned s = 0;
    for (int j = 0; j < NBIN / 1024; ++j) s += hist[base + j];
    part[t] = s;
    __syncthreads();
    for (int off = 1; off < 1024; off <<= 1) {
        unsigned v = (t >= off) ? part[t - off] : 0u;
        __syncthreads();
        part[t] += v;
        __syncthreads();
    }
    unsigned run = (t == 0) ? 0u : part[t - 1];
    for (int j = 0; j < NBIN / 1024; ++j) {
        unsigned tmp = hist[base + j];
        hist[base + j] = run;
        run += tmp;
    }
}

// ---------------------------------------------------------------------------
// Sort step 3: scatter (4 pts/thread vectorized xyz reads); stores u4 + orig.
// Bin-internal order is race-dependent, but output values are per-original-
// point and written to the original row -> deterministic d_out.
// ---------------------------------------------------------------------------
__global__ __launch_bounds__(256) void scatter_kernel(
    const float* __restrict__ xyz, unsigned* __restrict__ start,
    vf4* __restrict__ u4s, int* __restrict__ orig, int n)
{
    int t = blockIdx.x * 256 + threadIdx.x;
    int p = t * 4;
    if (p >= n) return;
    float U[4][3];
    int cnt = (p + 3 < n) ? 4 : (n - p);
    if (cnt == 4) {
        vf4 a = *(const vf4*)(xyz + (size_t)p * 3);
        vf4 b = *(const vf4*)(xyz + (size_t)p * 3 + 4);
        vf4 c = *(const vf4*)(xyz + (size_t)p * 3 + 8);
        U[0][0]=a.x; U[0][1]=a.y; U[0][2]=a.z;
        U[1][0]=a.w; U[1][1]=b.x; U[1][2]=b.y;
        U[2][0]=b.z; U[2][1]=b.w; U[2][2]=c.x;
        U[3][0]=c.y; U[3][1]=c.z; U[3][2]=c.w;
    } else {
        for (int q = 0; q < cnt; ++q) {
            U[q][0]=xyz[(size_t)(p+q)*3+0];
            U[q][1]=xyz[(size_t)(p+q)*3+1];
            U[q][2]=xyz[(size_t)(p+q)*3+2];
        }
    }
#pragma unroll
    for (int q = 0; q < 4; ++q) {
        if (q >= cnt) break;
        float ux = U[q][0]*0.5f+0.5f, uy = U[q][1]*0.5f+0.5f, uz = U[q][2]*0.5f+0.5f;
        unsigned pos = atomicAdd(&start[bin_of(ux,uy,uz)], 1u);
        orig[pos] = p + q;
        vf4 r; r.x = ux; r.y = uy; r.z = uz; r.w = 0.0f;
        u4s[pos] = r;
    }
}

// ---------------------------------------------------------------------------
// Fused gather+output: point-major over SORTED points. One thread = one
// point, all 16 levels (2-level interleave -> 16 loads in flight), writes
// the final 128B row directly to out[orig[i]]. No ws round-trip.
// ---------------------------------------------------------------------------
__global__ __launch_bounds__(256) void ngp_fused(
    const vf4* __restrict__ u4s,
    const unsigned* __restrict__ htab,
    const int* __restrict__ resolutions,
    const int* __restrict__ orig,
    float* __restrict__ out, int n)
{
    int i = blockIdx.x * 256 + threadIdx.x;
    if (i >= n) return;

    vf4 u = u4s[i];
    int op = orig[i];

    float acc[NLV * 2];

#pragma unroll
    for (int Lp = 0; Lp < NLV / 2; ++Lp) {
        unsigned idx[2][8];
        float wxs[2], wyz[2][4];
#pragma unroll
        for (int s = 0; s < 2; ++s) {
            int L = 2 * Lp + s;
            float res = (float)resolutions[L];
            float px = u.x * res, py = u.y * res, pz = u.z * res;
            float fx = floorf(px), fy = floorf(py), fz = floorf(pz);
            float wxl = px - fx, wyl = py - fy, wzl = pz - fz;
            unsigned cx = (unsigned)fx, cy = (unsigned)fy, cz = (unsigned)fz;
            unsigned hx0 = cx, hx1 = cx + 1u;
            unsigned hy0 = cy * P1, hy1 = hy0 + P1;
            unsigned hz0 = cz * P2, hz1 = hz0 + P2;
#pragma unroll
            for (int c = 0; c < 8; ++c)
                idx[s][c] = ((((c & 1) ? hx1 : hx0) ^
                              ((c & 2) ? hy1 : hy0) ^
                              ((c & 4) ? hz1 : hz0)) & TMASK);
            float vy = 1.0f - wyl, vz = 1.0f - wzl;
            wxs[s] = wxl;
            wyz[s][0] = vy * vz;  wyz[s][1] = wyl * vz;
            wyz[s][2] = vy * wzl; wyz[s][3] = wyl * wzl;
        }

        unsigned d[2][8];
#pragma unroll
        for (int s = 0; s < 2; ++s) {
            const unsigned* __restrict__ tab = htab + (size_t)(2 * Lp + s) * TBL;
#pragma unroll
            for (int c = 0; c < 8; ++c)
                d[s][c] = tab[idx[s][c]];
        }

#pragma unroll
        for (int s = 0; s < 2; ++s) {
            float vx = 1.0f - wxs[s];
            float a0 = 0.0f, a1 = 0.0f;
#pragma unroll
            for (int c = 0; c < 8; ++c) {
                float w = wyz[s][c >> 1] * ((c & 1) ? wxs[s] : vx);
                vf2 f = h2_to_f2(d[s][c]);
                a0 += f.x * w;
                a1 += f.y * w;
            }
            acc[(2 * Lp + s) * 2 + 0] = a0;
            acc[(2 * Lp + s) * 2 + 1] = a1;
        }
    }

    vf4* o = (vf4*)(out + (size_t)op * (NLV * 2));
#pragma unroll
    for (int j = 0; j < 8; ++j) {
        vf4 r; r.x = acc[j * 4 + 0]; r.y = acc[j * 4 + 1];
        r.z = acc[j * 4 + 2]; r.w = acc[j * 4 + 3];
        o[j] = r;
    }
}

// ---------------------------------------------------------------------------
// Fallback: single-pass point-major f32 kernel (ws too small).
// ---------------------------------------------------------------------------
__global__ __launch_bounds__(256) void ngp_encode_kernel(
    const float* __restrict__ xyz,
    const float* __restrict__ tables,
    const int* __restrict__ resolutions,
    float* __restrict__ out,
    int n)
{
    int p = blockIdx.x * blockDim.x + threadIdx.x;
    if (p >= n) return;

    float x = xyz[(size_t)p * 3 + 0];
    float y = xyz[(size_t)p * 3 + 1];
    float z = xyz[(size_t)p * 3 + 2];
    float ux = x * 0.5f + 0.5f;
    float uy = y * 0.5f + 0.5f;
    float uz = z * 0.5f + 0.5f;

    float acc[NLV * 2];

#pragma unroll
    for (int L = 0; L < NLV; ++L) {
        float res = (float)resolutions[L];
        float px = ux * res, py = uy * res, pz = uz * res;
        float fx = floorf(px), fy = floorf(py), fz = floorf(pz);
        float wx = px - fx, wy = py - fy, wz = pz - fz;
        unsigned cx = (unsigned)fx, cy = (unsigned)fy, cz = (unsigned)fz;
        unsigned hx0 = cx, hx1 = cx + 1u;
        unsigned hy0 = cy * P1, hy1 = hy0 + P1;
        unsigned hz0 = cz * P2, hz1 = hz0 + P2;
        const vf2* __restrict__ tab = (const vf2*)tables + (size_t)L * TBL;
        float vx = 1.0f - wx, vy = 1.0f - wy, vz = 1.0f - wz;
        float a0 = 0.0f, a1 = 0.0f;
#pragma unroll
        for (int c = 0; c < 8; ++c) {
            unsigned h = ((c & 1) ? hx1 : hx0) ^
                         ((c & 2) ? hy1 : hy0) ^
                         ((c & 4) ? hz1 : hz0);
            vf2 f = tab[h & TMASK];
            float w = ((c & 1) ? wx : vx) *
                      ((c & 2) ? wy : vy) *
                      ((c & 4) ? wz : vz);
            a0 += f.x * w;
            a1 += f.y * w;
        }
        acc[L * 2 + 0] = a0;
        acc[L * 2 + 1] = a1;
    }

    vf4* o = (vf4*)(out + (size_t)p * (NLV * 2));
#pragma unroll
    for (int i = 0; i < 8; ++i) {
        vf4 r; r.x = acc[i * 4 + 0]; r.y = acc[i * 4 + 1];
        r.z = acc[i * 4 + 2]; r.w = acc[i * 4 + 3];
        o[i] = r;
    }
}

extern "C" void kernel_launch(void* const* d_in, const int* in_sizes, int n_in,
                              void* d_out, int out_size, void* d_ws, size_t ws_size,
                              hipStream_t stream) {
    const float* xyz = (const float*)d_in[0];
    const float* tables = (const float*)d_in[1];
    const int* resolutions = (const int*)d_in[2];
    float* out = (float*)d_out;

    int n = in_sizes[0] / 3;
    const int totalEntries = NLV * (int)TBL;

    const size_t tabBytes  = (size_t)totalEntries * 4;      // 33.5 MB
    const size_t u4Bytes   = (size_t)n * sizeof(vf4);       // 33.5 MB
    const size_t origBytes = (size_t)n * 4;                 // 8.4 MB
    const size_t histBytes = (size_t)NBIN * 4;              // 128 KB
    const size_t need = tabBytes + u4Bytes + origBytes + histBytes;

    if (ws_size >= need) {
        char* base = (char*)d_ws;
        unsigned* htab  = (unsigned*)base;                       base += tabBytes;
        vf4*      u4s   = (vf4*)base;                            base += u4Bytes;
        int*      orig  = (int*)base;                            base += origBytes;
        unsigned* hist  = (unsigned*)base;

        hipMemsetAsync(hist, 0, histBytes, stream);

        int gridC = (totalEntries / 2 + 255) / 256;
        hipLaunchKernelGGL(convert_tables, dim3(gridC), dim3(256), 0, stream,
                           tables, htab, totalEntries);

        int grid4 = ((n + 3) / 4 + 255) / 256;
        hipLaunchKernelGGL(hist_kernel, dim3(grid4), dim3(256), 0, stream,
                           xyz, hist, n);
        hipLaunchKernelGGL(scan_bins, dim3(1), dim3(1024), 0, stream, hist);
        hipLaunchKernelGGL(scatter_kernel, dim3(grid4), dim3(256), 0, stream,
                           xyz, hist, u4s, orig, n);

        int gridP = (n + 255) / 256;
        hipLaunchKernelGGL(ngp_fused, dim3(gridP), dim3(256), 0, stream,
                           u4s, htab, resolutions, orig, out, n);
    } else {
        int grid = (n + 255) / 256;
        hipLaunchKernelGGL(ngp_encode_kernel, dim3(grid), dim3(256), 0, stream,
                           xyz, tables, resolutions, out, n);
    }
}

// Round 12
// 811.210 us; speedup vs baseline: 1.1368x; 1.1368x over previous
//
#include <hip/hip_runtime.h>
#include <hip/hip_fp16.h>

#define NLV 16
#define TBL (1u << 19)
#define TMASK (TBL - 1u)
#define P1 2654435761u
#define P2 805459861u
#define NBIN (1 << 15)   // 32^3 Morton bins

typedef float vf2 __attribute__((ext_vector_type(2)));
typedef float vf4 __attribute__((ext_vector_type(4)));
typedef unsigned vu2 __attribute__((ext_vector_type(2)));
typedef unsigned vu4 __attribute__((ext_vector_type(4)));
typedef int vi4 __attribute__((ext_vector_type(4)));

__device__ __forceinline__ vf2 h2_to_f2(unsigned bits) {
    union { unsigned u; __half2 h; } c; c.u = bits;
    float2 f = __half22float2(c.h);
    vf2 r; r.x = f.x; r.y = f.y; return r;
}
__device__ __forceinline__ unsigned f2_to_h2(float a, float b) {
    union { __half2 h; unsigned u; } c; c.h = __floats2half2_rn(a, b);
    return c.u;
}

__device__ __forceinline__ unsigned mort5(unsigned v) {
    v &= 31u;
    v = (v | (v << 16)) & 0x030000FFu;
    v = (v | (v << 8))  & 0x0300F00Fu;
    v = (v | (v << 4))  & 0x030C30C3u;
    v = (v | (v << 2))  & 0x09249249u;
    return v;
}

__device__ __forceinline__ unsigned bin_of(float ux, float uy, float uz) {
    unsigned bx = min(31u, (unsigned)(ux * 32.0f));
    unsigned by = min(31u, (unsigned)(uy * 32.0f));
    unsigned bz = min(31u, (unsigned)(uz * 32.0f));
    return mort5(bx) | (mort5(by) << 1) | (mort5(bz) << 2);
}

// ---------------------------------------------------------------------------
// Merged pre-pass: blocks [0, gridC) convert f32 tables -> fp16; blocks
// [gridC, gridC+gridH) histogram Morton bins. Independent work, one dispatch
// -> runs concurrently instead of serialized.
// ---------------------------------------------------------------------------
__global__ __launch_bounds__(256) void convert_and_hist(
    const float* __restrict__ tables, unsigned* __restrict__ htab, int total,
    const float* __restrict__ xyz, unsigned* __restrict__ hist, int n,
    int gridC)
{
    if ((int)blockIdx.x < gridC) {
        int i = blockIdx.x * 256 + threadIdx.x;
        int e0 = i * 2;
        if (e0 >= total) return;
        vf4 v = *(const vf4*)(tables + (size_t)e0 * 2);
        vu2 o; o.x = f2_to_h2(v.x, v.y); o.y = f2_to_h2(v.z, v.w);
        *(vu2*)(htab + e0) = o;
    } else {
        int t = (blockIdx.x - gridC) * 256 + threadIdx.x;
        int p = t * 4;
        if (p >= n) return;
        if (p + 3 < n) {
            vf4 a = *(const vf4*)(xyz + (size_t)p * 3);
            vf4 b = *(const vf4*)(xyz + (size_t)p * 3 + 4);
            vf4 c = *(const vf4*)(xyz + (size_t)p * 3 + 8);
            atomicAdd(&hist[bin_of(a.x*0.5f+0.5f, a.y*0.5f+0.5f, a.z*0.5f+0.5f)], 1u);
            atomicAdd(&hist[bin_of(a.w*0.5f+0.5f, b.x*0.5f+0.5f, b.y*0.5f+0.5f)], 1u);
            atomicAdd(&hist[bin_of(b.z*0.5f+0.5f, b.w*0.5f+0.5f, c.x*0.5f+0.5f)], 1u);
            atomicAdd(&hist[bin_of(c.y*0.5f+0.5f, c.z*0.5f+0.5f, c.w*0.5f+0.5f)], 1u);
        } else {
            for (int q = 0; q < 4 && p + q < n; ++q) {
                float ux = xyz[(size_t)(p+q)*3+0]*0.5f+0.5f;
                float uy = xyz[(size_t)(p+q)*3+1]*0.5f+0.5f;
                float uz = xyz[(size_t)(p+q)*3+2]*0.5f+0.5f;
                atomicAdd(&hist[bin_of(ux,uy,uz)], 1u);
            }
        }
    }
}

// ---------------------------------------------------------------------------
// Sort step 2: exclusive scan of NBIN counters (single block).
// ---------------------------------------------------------------------------
__global__ __launch_bounds__(1024) void scan_bins(unsigned* __restrict__ hist)
{
    __shared__ unsigned part[1024];
    int t = threadIdx.x;
    int base = t * (NBIN / 1024);
    unsigned s = 0;
    for (int j = 0; j < NBIN / 1024; ++j) s += hist[base + j];
    part[t] = s;
    __syncthreads();
    for (int off = 1; off < 1024; off <<= 1) {
        unsigned v = (t >= off) ? part[t - off] : 0u;
        __syncthreads();
        part[t] += v;
        __syncthreads();
    }
    unsigned run = (t == 0) ? 0u : part[t - 1];
    for (int j = 0; j < NBIN / 1024; ++j) {
        unsigned tmp = hist[base + j];
        hist[base + j] = run;
        run += tmp;
    }
}

// ---------------------------------------------------------------------------
// Sort step 3: scatter (4 pts/thread vectorized xyz reads); stores u4 + orig.
// Bin-internal order is race-dependent, but output values are per-original-
// point and written to the original row -> deterministic d_out.
// ---------------------------------------------------------------------------
__global__ __launch_bounds__(256) void scatter_kernel(
    const float* __restrict__ xyz, unsigned* __restrict__ start,
    vf4* __restrict__ u4s, int* __restrict__ orig, int n)
{
    int t = blockIdx.x * 256 + threadIdx.x;
    int p = t * 4;
    if (p >= n) return;
    float U[4][3];
    int cnt = (p + 3 < n) ? 4 : (n - p);
    if (cnt == 4) {
        vf4 a = *(const vf4*)(xyz + (size_t)p * 3);
        vf4 b = *(const vf4*)(xyz + (size_t)p * 3 + 4);
        vf4 c = *(const vf4*)(xyz + (size_t)p * 3 + 8);
        U[0][0]=a.x; U[0][1]=a.y; U[0][2]=a.z;
        U[1][0]=a.w; U[1][1]=b.x; U[1][2]=b.y;
        U[2][0]=b.z; U[2][1]=b.w; U[2][2]=c.x;
        U[3][0]=c.y; U[3][1]=c.z; U[3][2]=c.w;
    } else {
        for (int q = 0; q < cnt; ++q) {
            U[q][0]=xyz[(size_t)(p+q)*3+0];
            U[q][1]=xyz[(size_t)(p+q)*3+1];
            U[q][2]=xyz[(size_t)(p+q)*3+2];
        }
    }
#pragma unroll
    for (int q = 0; q < 4; ++q) {
        if (q >= cnt) break;
        float ux = U[q][0]*0.5f+0.5f, uy = U[q][1]*0.5f+0.5f, uz = U[q][2]*0.5f+0.5f;
        unsigned pos = atomicAdd(&start[bin_of(ux,uy,uz)], 1u);
        orig[pos] = p + q;
        vf4 r; r.x = ux; r.y = uy; r.z = uz; r.w = 0.0f;
        u4s[pos] = r;
    }
}

// ---------------------------------------------------------------------------
// Pass 1: level-major gather over SORTED points (R9/R10 proven config),
// launched as TWO dispatches (Lbase=0 and 8) for rocprof attribution.
// ---------------------------------------------------------------------------
__global__ __launch_bounds__(256) void ngp_gather_s(
    const vf4* __restrict__ u4s,
    const unsigned* __restrict__ htab,
    const int* __restrict__ resolutions,
    unsigned* __restrict__ wsout,
    int n, int nbPerLevel, int Lbase)
{
    int L = Lbase + blockIdx.x / nbPerLevel;
    int chunk = blockIdx.x % nbPerLevel;
    int p0 = chunk * 1024 + (int)threadIdx.x;

    float res = (float)resolutions[L];
    const unsigned* __restrict__ tab = htab + (size_t)L * TBL;
    unsigned* __restrict__ wl = wsout + (size_t)L * n;

    unsigned idx[4][8];
    float wx[4], wyz[4][4];
    bool valid[4];

#pragma unroll
    for (int q = 0; q < 4; ++q) {
        int p = p0 + q * 256;
        valid[q] = (p < n);
        int pp = valid[q] ? p : 0;
        vf4 u = u4s[pp];
        float px = u.x * res, py = u.y * res, pz = u.z * res;
        float fx = floorf(px), fy = floorf(py), fz = floorf(pz);
        float wxl = px - fx, wyl = py - fy, wzl = pz - fz;
        unsigned cx = (unsigned)fx, cy = (unsigned)fy, cz = (unsigned)fz;
        unsigned hx0 = cx, hx1 = cx + 1u;
        unsigned hy0 = cy * P1, hy1 = hy0 + P1;
        unsigned hz0 = cz * P2, hz1 = hz0 + P2;
#pragma unroll
        for (int c = 0; c < 8; ++c)
            idx[q][c] = ((((c & 1) ? hx1 : hx0) ^
                          ((c & 2) ? hy1 : hy0) ^
                          ((c & 4) ? hz1 : hz0)) & TMASK);
        float vy = 1.0f - wyl, vz = 1.0f - wzl;
        wx[q] = wxl;
        wyz[q][0] = vy * vz;  wyz[q][1] = wyl * vz;
        wyz[q][2] = vy * wzl; wyz[q][3] = wyl * wzl;
    }

    unsigned d[4][8];
#pragma unroll
    for (int q = 0; q < 4; ++q)
#pragma unroll
        for (int c = 0; c < 8; ++c)
            d[q][c] = tab[idx[q][c]];

#pragma unroll
    for (int q = 0; q < 4; ++q) {
        float vx = 1.0f - wx[q];
        float a0 = 0.0f, a1 = 0.0f;
#pragma unroll
        for (int c = 0; c < 8; ++c) {
            float w = wyz[q][c >> 1] * ((c & 1) ? wx[q] : vx);
            vf2 f = h2_to_f2(d[q][c]);
            a0 += f.x * w;
            a1 += f.y * w;
        }
        int p = p0 + q * 256;
        if (valid[q]) wl[p] = f2_to_h2(a0, a1);
    }
}

// ---------------------------------------------------------------------------
// Pass 2: vectorized transpose-merge (4 pts/thread), scatter full 128B rows.
// ---------------------------------------------------------------------------
__global__ __launch_bounds__(256) void ngp_finalize_s(
    const unsigned* __restrict__ ws, const int* __restrict__ orig,
    float* __restrict__ out, int n)
{
    int t = blockIdx.x * 256 + threadIdx.x;
    int i = t * 4;
    if (i >= n) return;

    if (i + 3 < n && (n & 3) == 0) {
        vu4 m[NLV];
#pragma unroll
        for (int L = 0; L < NLV; ++L)
            m[L] = *(const vu4*)(ws + (size_t)L * n + i);
        vi4 og = *(const vi4*)(orig + i);
#pragma unroll
        for (int pt = 0; pt < 4; ++pt) {
            int op = pt == 0 ? og.x : pt == 1 ? og.y : pt == 2 ? og.z : og.w;
            vf4* o = (vf4*)(out + (size_t)op * (NLV * 2));
#pragma unroll
            for (int j = 0; j < 8; ++j) {
                unsigned ba = pt == 0 ? m[2 * j].x : pt == 1 ? m[2 * j].y
                             : pt == 2 ? m[2 * j].z : m[2 * j].w;
                unsigned bb = pt == 0 ? m[2 * j + 1].x : pt == 1 ? m[2 * j + 1].y
                             : pt == 2 ? m[2 * j + 1].z : m[2 * j + 1].w;
                vf2 ga = h2_to_f2(ba), gb = h2_to_f2(bb);
                vf4 r; r.x = ga.x; r.y = ga.y; r.z = gb.x; r.w = gb.y;
                o[j] = r;
            }
        }
    } else {
        for (int pt = 0; pt < 4 && i + pt < n; ++pt) {
            int op = orig[i + pt];
            vf4* o = (vf4*)(out + (size_t)op * (NLV * 2));
#pragma unroll
            for (int j = 0; j < 8; ++j) {
                vf2 ga = h2_to_f2(ws[(size_t)(2 * j) * n + i + pt]);
                vf2 gb = h2_to_f2(ws[(size_t)(2 * j + 1) * n + i + pt]);
                vf4 r; r.x = ga.x; r.y = ga.y; r.z = gb.x; r.w = gb.y;
                o[j] = r;
            }
        }
    }
}

// ---------------------------------------------------------------------------
// Fallback: single-pass point-major f32 kernel (ws too small).
// ---------------------------------------------------------------------------
__global__ __launch_bounds__(256) void ngp_encode_kernel(
    const float* __restrict__ xyz,
    const float* __restrict__ tables,
    const int* __restrict__ resolutions,
    float* __restrict__ out,
    int n)
{
    int p = blockIdx.x * blockDim.x + threadIdx.x;
    if (p >= n) return;

    float x = xyz[(size_t)p * 3 + 0];
    float y = xyz[(size_t)p * 3 + 1];
    float z = xyz[(size_t)p * 3 + 2];
    float ux = x * 0.5f + 0.5f;
    float uy = y * 0.5f + 0.5f;
    float uz = z * 0.5f + 0.5f;

    float acc[NLV * 2];

#pragma unroll
    for (int L = 0; L < NLV; ++L) {
        float res = (float)resolutions[L];
        float px = ux * res, py = uy * res, pz = uz * res;
        float fx = floorf(px), fy = floorf(py), fz = floorf(pz);
        float wx = px - fx, wy = py - fy, wz = pz - fz;
        unsigned cx = (unsigned)fx, cy = (unsigned)fy, cz = (unsigned)fz;
        unsigned hx0 = cx, hx1 = cx + 1u;
        unsigned hy0 = cy * P1, hy1 = hy0 + P1;
        unsigned hz0 = cz * P2, hz1 = hz0 + P2;
        const vf2* __restrict__ tab = (const vf2*)tables + (size_t)L * TBL;
        float vx = 1.0f - wx, vy = 1.0f - wy, vz = 1.0f - wz;
        float a0 = 0.0f, a1 = 0.0f;
#pragma unroll
        for (int c = 0; c < 8; ++c) {
            unsigned h = ((c & 1) ? hx1 : hx0) ^
                         ((c & 2) ? hy1 : hy0) ^
                         ((c & 4) ? hz1 : hz0);
            vf2 f = tab[h & TMASK];
            float w = ((c & 1) ? wx : vx) *
                      ((c & 2) ? wy : vy) *
                      ((c & 4) ? wz : vz);
            a0 += f.x * w;
            a1 += f.y * w;
        }
        acc[L * 2 + 0] = a0;
        acc[L * 2 + 1] = a1;
    }

    vf4* o = (vf4*)(out + (size_t)p * (NLV * 2));
#pragma unroll
    for (int i = 0; i < 8; ++i) {
        vf4 r; r.x = acc[i * 4 + 0]; r.y = acc[i * 4 + 1];
        r.z = acc[i * 4 + 2]; r.w = acc[i * 4 + 3];
        o[i] = r;
    }
}

extern "C" void kernel_launch(void* const* d_in, const int* in_sizes, int n_in,
                              void* d_out, int out_size, void* d_ws, size_t ws_size,
                              hipStream_t stream) {
    const float* xyz = (const float*)d_in[0];
    const float* tables = (const float*)d_in[1];
    const int* resolutions = (const int*)d_in[2];
    float* out = (float*)d_out;

    int n = in_sizes[0] / 3;
    const int totalEntries = NLV * (int)TBL;

    const size_t tabBytes  = (size_t)totalEntries * 4;      // 33.5 MB
    const size_t u4Bytes   = (size_t)n * sizeof(vf4);       // 33.5 MB
    const size_t origBytes = (size_t)n * 4;                 // 8.4 MB
    const size_t histBytes = (size_t)NBIN * 4;              // 128 KB
    const size_t wsoutBytes = (size_t)NLV * (size_t)n * 4;  // 134 MB
    const size_t need = tabBytes + u4Bytes + origBytes + histBytes + wsoutBytes;

    if (ws_size >= need) {
        char* base = (char*)d_ws;
        unsigned* htab  = (unsigned*)base;                       base += tabBytes;
        vf4*      u4s   = (vf4*)base;                            base += u4Bytes;
        int*      orig  = (int*)base;                            base += origBytes;
        unsigned* hist  = (unsigned*)base;                       base += histBytes;
        unsigned* wsout = (unsigned*)base;

        hipMemsetAsync(hist, 0, histBytes, stream);

        int gridC = (totalEntries / 2 + 255) / 256;
        int grid4 = ((n + 3) / 4 + 255) / 256;
        hipLaunchKernelGGL(convert_and_hist, dim3(gridC + grid4), dim3(256), 0,
                           stream, tables, htab, totalEntries, xyz, hist, n, gridC);

        hipLaunchKernelGGL(scan_bins, dim3(1), dim3(1024), 0, stream, hist);
        hipLaunchKernelGGL(scatter_kernel, dim3(grid4), dim3(256), 0, stream,
                           xyz, hist, u4s, orig, n);

        int nbPerLevel = (n + 1023) / 1024;
        int gridHalf = 8 * nbPerLevel;
        hipLaunchKernelGGL(ngp_gather_s, dim3(gridHalf), dim3(256), 0, stream,
                           u4s, htab, resolutions, wsout, n, nbPerLevel, 0);
        hipLaunchKernelGGL(ngp_gather_s, dim3(gridHalf), dim3(256), 0, stream,
                           u4s, htab, resolutions, wsout, n, nbPerLevel, 8);

        int gridF = ((n + 3) / 4 + 255) / 256;
        hipLaunchKernelGGL(ngp_finalize_s, dim3(gridF), dim3(256), 0, stream,
                           wsout, orig, out, n);
    } else {
        int grid = (n + 255) / 256;
        hipLaunchKernelGGL(ngp_encode_kernel, dim3(grid), dim3(256), 0, stream,
                           xyz, tables, resolutions, out, n);
    }
}